// Round 6
// baseline (358.622 us; speedup 1.0000x reference)
//
#include <hip/hip_runtime.h>
#include <hip/hip_bf16.h>
#include <cstdint>

typedef __attribute__((ext_vector_type(8))) short bf16x8;
typedef __attribute__((ext_vector_type(4))) float f32x4;

#define LDT 72    // proj LDS row stride (bf16)
#define PLDT 72   // attn P^T LDS row stride (bf16)

static __device__ __forceinline__ unsigned short f2bf(float x) {
    __hip_bfloat16 h = __float2bfloat16(x);
    union { __hip_bfloat16 b; unsigned short u; } c; c.b = h; return c.u;
}
static __device__ __forceinline__ float bf2f(unsigned short b) {
    union { float f; uint32_t u; } v; v.u = ((uint32_t)b) << 16;
    return v.f;
}
static __device__ __forceinline__ float exp2b(float x) {
    return __builtin_amdgcn_exp2f(x);   // raw v_exp_f32
}
static __device__ __forceinline__ unsigned int cvt_pk_bf16(float lo, float hi) {
    unsigned int r;
    asm("v_cvt_pk_bf16_f32 %0, %1, %2" : "=v"(r) : "v"(lo), "v"(hi));
    return r;
}

// ---------------------------------------------------------------------------
// Fused projection GEMMs: z=0: Q, z=1: K (both (B,H,S,64)), z=2: V^T (B,H,64,S)
// Y[m][e] = sum_k X[m][k] * W[e][k] + bias[e].  M=4096, N=1024, K=1024.
// One dispatch, grid (32,8,3) = 768 blocks -> 3 blocks/CU.
// ---------------------------------------------------------------------------
__global__ __launch_bounds__(256) void proj_gemm_all(
    const float* __restrict__ Xq, const float* __restrict__ Xk, const float* __restrict__ Xv,
    const float* __restrict__ Wqp, const float* __restrict__ Wkp, const float* __restrict__ Wvp,
    const float* __restrict__ bqp, const float* __restrict__ bkp, const float* __restrict__ bvp,
    unsigned short* __restrict__ dq, unsigned short* __restrict__ dk, unsigned short* __restrict__ dv) {
    __shared__ unsigned short a_lds[128 * LDT];
    __shared__ unsigned short b_lds[128 * LDT];

    const int z = blockIdx.z;
    const float* X = (z == 0) ? Xq : (z == 1) ? Xk : Xv;
    const float* W = (z == 0) ? Wqp : (z == 1) ? Wkp : Wvp;
    const float* bias = (z == 0) ? bqp : (z == 1) ? bkp : bvp;
    unsigned short* dst = (z == 0) ? dq : (z == 1) ? dk : dv;
    const bool vtrans = (z == 2);

    const int tid = threadIdx.x;
    const int lane = tid & 63;
    const int w = tid >> 6;
    const int lr = lane & 15;
    const int lg = lane >> 4;
    const int m0 = blockIdx.x * 128;
    const int e0 = blockIdx.y * 128;
    const int wrow = (w >> 1) * 64;
    const int wcol = (w & 1) * 64;

    f32x4 acc[4][4] = {};

    for (int k0 = 0; k0 < 1024; k0 += 64) {
        __syncthreads();
        for (int i = 0; i < 8; ++i) {
            int f = tid + 256 * i;
            int row = f >> 4;
            int c4 = (f & 15) << 2;
            float4 xa = *(const float4*)(X + (size_t)(m0 + row) * 1024 + k0 + c4);
            ushort4 pa;
            pa.x = f2bf(xa.x); pa.y = f2bf(xa.y); pa.z = f2bf(xa.z); pa.w = f2bf(xa.w);
            *(ushort4*)(a_lds + row * LDT + c4) = pa;
            float4 xb = *(const float4*)(W + (size_t)(e0 + row) * 1024 + k0 + c4);
            ushort4 pb;
            pb.x = f2bf(xb.x); pb.y = f2bf(xb.y); pb.z = f2bf(xb.z); pb.w = f2bf(xb.w);
            *(ushort4*)(b_lds + row * LDT + c4) = pb;
        }
        __syncthreads();

        for (int ks = 0; ks < 2; ++ks) {
            const int kk = ks * 32 + lg * 8;
            bf16x8 af[4], bfr[4];
            for (int mt = 0; mt < 4; ++mt)
                af[mt] = *(const bf16x8*)(a_lds + (wrow + mt * 16 + lr) * LDT + kk);
            for (int nt = 0; nt < 4; ++nt)
                bfr[nt] = *(const bf16x8*)(b_lds + (wcol + nt * 16 + lr) * LDT + kk);
            for (int mt = 0; mt < 4; ++mt)
                for (int nt = 0; nt < 4; ++nt)
                    acc[mt][nt] = __builtin_amdgcn_mfma_f32_16x16x32_bf16(
                        af[mt], bfr[nt], acc[mt][nt], 0, 0, 0);
        }
    }

    for (int mt = 0; mt < 4; ++mt)
        for (int nt = 0; nt < 4; ++nt)
            for (int i = 0; i < 4; ++i) {
                int m = m0 + wrow + mt * 16 + lg * 4 + i;
                int e = e0 + wcol + nt * 16 + lr;
                float val = acc[mt][nt][i] + bias[e];
                int b = m >> 11, s = m & 2047;
                int h = e >> 6, d = e & 63;
                if (vtrans)
                    dst[(((size_t)b * 16 + h) * 64 + d) * 2048 + s] = f2bf(val);
                else
                    dst[(((size_t)b * 16 + h) * 2048 + s) * 64 + d] = f2bf(val);
            }
}

// ---------------------------------------------------------------------------
// Flash attention v6: 16 q-rows per wave, 1024 blocks -> 4 waves/SIMD by TLP.
// NO launch_bounds occupancy hint (r5's (256,4) clamped VGPR to 64 -> spills).
// V fragments loaded AFTER the P-write so their 32 VGPRs don't overlap the
// softmax live range (target <=128 VGPR so 4 waves/SIMD are resident).
// Barrier-free; K/V direct from L2 (T1 XCD swizzle). S^T = K.Q^T, in-register
// online softmax (exp2 domain), P^T via per-wave LDS, O^T = V^T.P^T.
// ---------------------------------------------------------------------------
__global__ __launch_bounds__(256) void attn_kernel(
    const unsigned short* __restrict__ Qh,
    const unsigned short* __restrict__ Kh,
    const unsigned short* __restrict__ VTh,
    const unsigned char* __restrict__ mask,
    float* __restrict__ Out) {
    __shared__ unsigned short pbuf[4][2176];  // per-wave: P^T [16][PLDT] / epilogue [16][68] f32

    const int tid = threadIdx.x;
    const int lane = tid & 63;
    const int w = tid >> 6;
    const int lr = lane & 15;
    const int lg = lane >> 4;

    // T1 XCD swizzle: 1024 workgroups, 128 per XCD -> 4 heads' K/V per XCD L2
    const int bid = blockIdx.x;
    const int wk = (bid & 7) * 128 + (bid >> 3);
    const int x = wk & 31;        // q-tile (64 q per block)
    const int bh = wk >> 5;       // 0..31
    const int h = bh & 15;
    const int b = bh >> 4;
    const int q0 = x * 64 + w * 16;

    const size_t headoff = (((size_t)b * 16) + h) * 2048 * 64;
    const unsigned short* Qp = Qh + headoff;
    const unsigned short* VTp = VTh + headoff;  // [64][2048]
    const unsigned char* maskp = mask + b * 2048;
    unsigned short* pw = pbuf[w];

    const unsigned short* kptr = Kh + headoff + lr * 64 + lg * 8;   // += 4096/iter
    const unsigned short* vptr = VTp + lr * 2048 + lg * 8;          // += 64/iter

    // Q as B-operand (col=q=lr, k=lg*8+j), scaled by 1/sqrt(64)*log2(e)
    const float qscale = 0.125f * 1.44269504088896340736f;
    bf16x8 qf[2];
#pragma unroll
    for (int ks = 0; ks < 2; ++ks) {
        bf16x8 t = *(const bf16x8*)(Qp + (size_t)(q0 + lr) * 64 + ks * 32 + lg * 8);
#pragma unroll
        for (int j = 0; j < 8; ++j)
            t[j] = (short)f2bf(bf2f((unsigned short)t[j]) * qscale);
        qf[ks] = t;
    }

    f32x4 o[4] = {};          // O^T: lane holds q=lr, d = mt*16 + lg*4 + i
    float mrow = -INFINITY;
    float lsum = 0.f;

#pragma unroll 1
    for (int t = 0; t < 32; ++t) {
        // K fragments (8 x b128 from global/L2); die after QK^T
        bf16x8 kf[2][4];
#pragma unroll
        for (int ks = 0; ks < 2; ++ks)
#pragma unroll
            for (int mt = 0; mt < 4; ++mt)
                kf[ks][mt] = *(const bf16x8*)(kptr + mt * 1024 + ks * 32);
        kptr += 4096;

        // S^T[kv][q] = K . Q^T
        f32x4 s[4] = {};
        __builtin_amdgcn_s_setprio(1);
#pragma unroll
        for (int ks = 0; ks < 2; ++ks)
#pragma unroll
            for (int mt = 0; mt < 4; ++mt)
                s[mt] = __builtin_amdgcn_mfma_f32_16x16x32_bf16(kf[ks][mt], qf[ks], s[mt], 0, 0, 0);
        __builtin_amdgcn_s_setprio(0);

        unsigned long long mbits = __ballot(maskp[t * 64 + lane] != 0);
        if (mbits) {
#pragma unroll
            for (int mt = 0; mt < 4; ++mt)
#pragma unroll
                for (int i = 0; i < 4; ++i)
                    if ((mbits >> (mt * 16 + lg * 4 + i)) & 1ull) s[mt][i] = -1e30f;
        }

        // online softmax: lane owns q=lr (16 kv in-lane; lanes lg=0..3 share q)
        float mx01 = fmaxf(fmaxf(s[0][0], s[0][1]), fmaxf(s[0][2], s[0][3]));
        float mx23 = fmaxf(fmaxf(s[1][0], s[1][1]), fmaxf(s[1][2], s[1][3]));
        float mx45 = fmaxf(fmaxf(s[2][0], s[2][1]), fmaxf(s[2][2], s[2][3]));
        float mx67 = fmaxf(fmaxf(s[3][0], s[3][1]), fmaxf(s[3][2], s[3][3]));
        float mx = fmaxf(fmaxf(mx01, mx23), fmaxf(mx45, mx67));
        mx = fmaxf(mx, __shfl_xor(mx, 16));
        mx = fmaxf(mx, __shfl_xor(mx, 32));
        if (!__all(mx <= mrow + 8.0f)) {  // defer-max (T13)
            float nm = fmaxf(mrow, mx);
            float f = exp2b(mrow - nm);
            mrow = nm;
            lsum *= f;
#pragma unroll
            for (int mt = 0; mt < 4; ++mt)
#pragma unroll
                for (int i = 0; i < 4; ++i) o[mt][i] *= f;
        }
        float p[4][4];
        float ls = 0.f;
#pragma unroll
        for (int mt = 0; mt < 4; ++mt)
#pragma unroll
            for (int i = 0; i < 4; ++i) {
                p[mt][i] = exp2b(s[mt][i] - mrow);
                ls += p[mt][i];
            }
        ls += __shfl_xor(ls, 16);
        ls += __shfl_xor(ls, 32);
        lsum += ls;

        // P^T -> per-wave LDS: row q=lr, kv = mt*16 + lg*4 + {0..3}
#pragma unroll
        for (int mt = 0; mt < 4; ++mt) {
            uint2 pr;
            pr.x = cvt_pk_bf16(p[mt][0], p[mt][1]);
            pr.y = cvt_pk_bf16(p[mt][2], p[mt][3]);
            *(uint2*)(&pw[lr * PLDT + mt * 16 + lg * 4]) = pr;
        }

        // V fragments (loaded HERE so they don't overlap softmax's live range)
        bf16x8 vf[2][4];
#pragma unroll
        for (int ks = 0; ks < 2; ++ks)
#pragma unroll
            for (int mt = 0; mt < 4; ++mt)
                vf[ks][mt] = *(const bf16x8*)(vptr + mt * 32768 + ks * 32);
        vptr += 64;

        // O^T += V^T . P^T
        __builtin_amdgcn_s_setprio(1);
#pragma unroll
        for (int ks = 0; ks < 2; ++ks) {
            bf16x8 pfr = *(const bf16x8*)(&pw[lr * PLDT + ks * 32 + lg * 8]);
#pragma unroll
            for (int mt = 0; mt < 4; ++mt)
                o[mt] = __builtin_amdgcn_mfma_f32_16x16x32_bf16(vf[ks][mt], pfr, o[mt], 0, 0, 0);
        }
        __builtin_amdgcn_s_setprio(0);
    }

    // epilogue (wave-private): transpose O^T -> [q][d] then coalesced stores
    float* ep = (float*)pw;  // 16*68 floats = 4352B
    float rinv = 1.0f / lsum;
#pragma unroll
    for (int mt = 0; mt < 4; ++mt)
#pragma unroll
        for (int i = 0; i < 4; ++i)
            ep[lr * 68 + mt * 16 + lg * 4 + i] = o[mt][i] * rinv;
#pragma unroll
    for (int j = 0; j < 4; ++j) {
        int id = lane + 64 * j;     // 256 float4 = 16 q x 16
        int row = id >> 4;
        int c4 = (id & 15) << 2;
        float4 val = *(const float4*)(&ep[row * 68 + c4]);
        *(float4*)(&Out[((size_t)b * 2048 + q0 + row) * 1024 + h * 64 + c4]) = val;
    }
}

extern "C" void kernel_launch(void* const* d_in, const int* in_sizes, int n_in,
                              void* d_out, int out_size, void* d_ws, size_t ws_size,
                              hipStream_t stream) {
    const float* v = (const float*)d_in[0];
    const float* k = (const float*)d_in[1];
    const float* q = (const float*)d_in[2];
    const unsigned char* mask = (const unsigned char*)d_in[3];
    const float* Wq = (const float*)d_in[4];
    const float* bq = (const float*)d_in[5];
    const float* Wk = (const float*)d_in[6];
    const float* bk = (const float*)d_in[7];
    const float* Wv = (const float*)d_in[8];
    const float* bv = (const float*)d_in[9];
    float* out = (float*)d_out;

    unsigned short* qws = (unsigned short*)d_ws;
    unsigned short* kws = qws + 4194304;
    unsigned short* vws = kws + 4194304;

    dim3 pgrid(32, 8, 3);
    proj_gemm_all<<<pgrid, 256, 0, stream>>>(q, k, v, Wq, Wk, Wv, bq, bk, bv,
                                             qws, kws, vws);

    attn_kernel<<<dim3(1024), 256, 0, stream>>>(qws, kws, vws, mask, out);
}

// Round 7
// 137.723 us; speedup vs baseline: 2.6039x; 2.6039x over previous
//
#include <hip/hip_runtime.h>
#include <hip/hip_bf16.h>
#include <cstdint>

typedef __attribute__((ext_vector_type(8))) short bf16x8;
typedef __attribute__((ext_vector_type(4))) float f32x4;

#define LDT 72    // LDS row stride (bf16): 144B rows -> 8-lane full-bank sweeps
#define PLDT 72

static __device__ __forceinline__ unsigned short f2bf(float x) {
    __hip_bfloat16 h = __float2bfloat16(x);
    union { __hip_bfloat16 b; unsigned short u; } c; c.b = h; return c.u;
}
static __device__ __forceinline__ float bf2f(unsigned short b) {
    union { float f; uint32_t u; } v; v.u = ((uint32_t)b) << 16;
    return v.f;
}
static __device__ __forceinline__ float exp2b(float x) {
    return __builtin_amdgcn_exp2f(x);
}
static __device__ __forceinline__ unsigned int cvt_pk_bf16(float lo, float hi) {
    unsigned int r;
    asm("v_cvt_pk_bf16_f32 %0, %1, %2" : "=v"(r) : "v"(lo), "v"(hi));
    return r;
}

// ---------------------------------------------------------------------------
// Fused projection GEMMs: z=0: Q, z=1: K (both (B,H,S,64)), z=2: V^T (B,H,64,S)
// ---------------------------------------------------------------------------
__global__ __launch_bounds__(256) void proj_gemm_all(
    const float* __restrict__ Xq, const float* __restrict__ Xk, const float* __restrict__ Xv,
    const float* __restrict__ Wqp, const float* __restrict__ Wkp, const float* __restrict__ Wvp,
    const float* __restrict__ bqp, const float* __restrict__ bkp, const float* __restrict__ bvp,
    unsigned short* __restrict__ dq, unsigned short* __restrict__ dk, unsigned short* __restrict__ dv) {
    __shared__ unsigned short a_lds[128 * LDT];
    __shared__ unsigned short b_lds[128 * LDT];

    const int z = blockIdx.z;
    const float* X = (z == 0) ? Xq : (z == 1) ? Xk : Xv;
    const float* W = (z == 0) ? Wqp : (z == 1) ? Wkp : Wvp;
    const float* bias = (z == 0) ? bqp : (z == 1) ? bkp : bvp;
    unsigned short* dst = (z == 0) ? dq : (z == 1) ? dk : dv;
    const bool vtrans = (z == 2);

    const int tid = threadIdx.x;
    const int lane = tid & 63;
    const int w = tid >> 6;
    const int lr = lane & 15;
    const int lg = lane >> 4;
    const int m0 = blockIdx.x * 128;
    const int e0 = blockIdx.y * 128;
    const int wrow = (w >> 1) * 64;
    const int wcol = (w & 1) * 64;

    f32x4 acc[4][4] = {};

    for (int k0 = 0; k0 < 1024; k0 += 64) {
        __syncthreads();
        for (int i = 0; i < 8; ++i) {
            int f = tid + 256 * i;
            int row = f >> 4;
            int c4 = (f & 15) << 2;
            float4 xa = *(const float4*)(X + (size_t)(m0 + row) * 1024 + k0 + c4);
            ushort4 pa;
            pa.x = f2bf(xa.x); pa.y = f2bf(xa.y); pa.z = f2bf(xa.z); pa.w = f2bf(xa.w);
            *(ushort4*)(a_lds + row * LDT + c4) = pa;
            float4 xb = *(const float4*)(W + (size_t)(e0 + row) * 1024 + k0 + c4);
            ushort4 pb;
            pb.x = f2bf(xb.x); pb.y = f2bf(xb.y); pb.z = f2bf(xb.z); pb.w = f2bf(xb.w);
            *(ushort4*)(b_lds + row * LDT + c4) = pb;
        }
        __syncthreads();

        for (int ks = 0; ks < 2; ++ks) {
            const int kk = ks * 32 + lg * 8;
            bf16x8 af[4], bfr[4];
            for (int mt = 0; mt < 4; ++mt)
                af[mt] = *(const bf16x8*)(a_lds + (wrow + mt * 16 + lr) * LDT + kk);
            for (int nt = 0; nt < 4; ++nt)
                bfr[nt] = *(const bf16x8*)(b_lds + (wcol + nt * 16 + lr) * LDT + kk);
            for (int mt = 0; mt < 4; ++mt)
                for (int nt = 0; nt < 4; ++nt)
                    acc[mt][nt] = __builtin_amdgcn_mfma_f32_16x16x32_bf16(
                        af[mt], bfr[nt], acc[mt][nt], 0, 0, 0);
        }
    }

    for (int mt = 0; mt < 4; ++mt)
        for (int nt = 0; nt < 4; ++nt)
            for (int i = 0; i < 4; ++i) {
                int m = m0 + wrow + mt * 16 + lg * 4 + i;
                int e = e0 + wcol + nt * 16 + lr;
                float val = acc[mt][nt][i] + bias[e];
                int b = m >> 11, s = m & 2047;
                int h = e >> 6, d = e & 63;
                if (vtrans)
                    dst[(((size_t)b * 16 + h) * 64 + d) * 2048 + s] = f2bf(val);
                else
                    dst[(((size_t)b * 16 + h) * 2048 + s) * 64 + d] = f2bf(val);
            }
}

// ---------------------------------------------------------------------------
// Flash attention v7: block-shared K/V LDS staging with COALESCED global
// loads (each wave reads contiguous 1KB; 8 cache lines/instr vs 16 scattered
// in v3-v6) + T14 async-split (next tile's loads issued before compute,
// written after barrier). 4 waves x 32 q, 512 blocks. Swapped orientation:
// S^T = K.Q^T, in-register online softmax, P^T per-wave LDS, O^T = V^T.P^T.
// ---------------------------------------------------------------------------
__global__ __launch_bounds__(256) void attn_kernel(
    const unsigned short* __restrict__ Qh,
    const unsigned short* __restrict__ Kh,
    const unsigned short* __restrict__ VTh,
    const unsigned char* __restrict__ mask,
    float* __restrict__ Out) {
    __shared__ unsigned short k_lds[64 * LDT];
    __shared__ unsigned short v_lds[64 * LDT];
    __shared__ unsigned short pbuf[4][32 * PLDT];  // per-wave P^T [q 32][kv 64]

    const int tid = threadIdx.x;
    const int lane = tid & 63;
    const int w = tid >> 6;
    const int lr = lane & 15;
    const int lg = lane >> 4;

    // T1 XCD swizzle: 512 workgroups, 64 per XCD
    const int bid = blockIdx.x;
    const int wk = (bid & 7) * 64 + (bid >> 3);
    const int x = wk & 15;
    const int bh = wk >> 4;
    const int h = bh & 15;
    const int b = bh >> 4;
    const int q0 = x * 128;

    const size_t headoff = (((size_t)b * 16) + h) * 2048 * 64;
    const unsigned short* Qp = Qh + headoff;
    const unsigned short* Kp = Kh + headoff;
    const unsigned short* VTp = VTh + headoff;  // [64][2048]
    const unsigned char* maskp = mask + b * 2048;
    unsigned short* pw = pbuf[w];

    // staging assignment: thread handles chunks tid and tid+256 of 512
    const int srow0 = tid >> 3;           // 0..31
    const int srow1 = srow0 + 32;         // 32..63
    const int sch = (tid & 7) * 8;        // element offset within row

    // Q as B-operand (col=q=lr, k=lg*8+j), scaled by 1/sqrt(64)*log2(e)
    const float qscale = 0.125f * 1.44269504088896340736f;
    bf16x8 qf[2][2];
#pragma unroll
    for (int qh = 0; qh < 2; ++qh) {
        int row = q0 + w * 32 + qh * 16 + lr;
#pragma unroll
        for (int ks = 0; ks < 2; ++ks) {
            bf16x8 t = *(const bf16x8*)(Qp + (size_t)row * 64 + ks * 32 + lg * 8);
#pragma unroll
            for (int j = 0; j < 8; ++j)
                t[j] = (short)f2bf(bf2f((unsigned short)t[j]) * qscale);
            qf[qh][ks] = t;
        }
    }

    f32x4 o[2][4] = {};
    float mrow[2] = {-INFINITY, -INFINITY};
    float lsum[2] = {0.f, 0.f};

    // prologue: load tile 0 into staging registers
    uint4 kr0 = *(const uint4*)(Kp + srow0 * 64 + sch);
    uint4 kr1 = *(const uint4*)(Kp + srow1 * 64 + sch);
    uint4 vr0 = *(const uint4*)(VTp + srow0 * 2048 + sch);
    uint4 vr1 = *(const uint4*)(VTp + srow1 * 2048 + sch);

#pragma unroll 1
    for (int t = 0; t < 32; ++t) {
        const int kv0 = t * 64;
        __syncthreads();   // all waves done reading previous tile
        *(uint4*)(k_lds + srow0 * LDT + sch) = kr0;
        *(uint4*)(k_lds + srow1 * LDT + sch) = kr1;
        *(uint4*)(v_lds + srow0 * LDT + sch) = vr0;
        *(uint4*)(v_lds + srow1 * LDT + sch) = vr1;
        __syncthreads();

        // T14: issue next tile's global loads now; consumed next iteration
        if (t < 31) {
            const int nv0 = kv0 + 64;
            kr0 = *(const uint4*)(Kp + (nv0 + srow0) * 64 + sch);
            kr1 = *(const uint4*)(Kp + (nv0 + srow1) * 64 + sch);
            vr0 = *(const uint4*)(VTp + srow0 * 2048 + nv0 + sch);
            vr1 = *(const uint4*)(VTp + srow1 * 2048 + nv0 + sch);
        }

        // K fragments from LDS
        bf16x8 kf[2][4];
#pragma unroll
        for (int ks = 0; ks < 2; ++ks)
#pragma unroll
            for (int mt = 0; mt < 4; ++mt)
                kf[ks][mt] = *(const bf16x8*)(k_lds + (mt * 16 + lr) * LDT + ks * 32 + lg * 8);

        // S^T[kv][q] = K . Q^T
        f32x4 s[2][4] = {};
        __builtin_amdgcn_s_setprio(1);
#pragma unroll
        for (int ks = 0; ks < 2; ++ks)
#pragma unroll
            for (int mt = 0; mt < 4; ++mt) {
                s[0][mt] = __builtin_amdgcn_mfma_f32_16x16x32_bf16(kf[ks][mt], qf[0][ks], s[0][mt], 0, 0, 0);
                s[1][mt] = __builtin_amdgcn_mfma_f32_16x16x32_bf16(kf[ks][mt], qf[1][ks], s[1][mt], 0, 0, 0);
            }
        __builtin_amdgcn_s_setprio(0);

        unsigned long long mbits = __ballot(maskp[kv0 + lane] != 0);
        if (mbits) {
#pragma unroll
            for (int qh = 0; qh < 2; ++qh)
#pragma unroll
                for (int mt = 0; mt < 4; ++mt)
#pragma unroll
                    for (int i = 0; i < 4; ++i)
                        if ((mbits >> (mt * 16 + lg * 4 + i)) & 1ull) s[qh][mt][i] = -1e30f;
        }

        // online softmax + P-pack per q-half
#pragma unroll
        for (int qh = 0; qh < 2; ++qh) {
            float mx = s[qh][0][0];
#pragma unroll
            for (int mt = 0; mt < 4; ++mt)
#pragma unroll
                for (int i = 0; i < 4; ++i) mx = fmaxf(mx, s[qh][mt][i]);
            mx = fmaxf(mx, __shfl_xor(mx, 16));
            mx = fmaxf(mx, __shfl_xor(mx, 32));
            if (!__all(mx <= mrow[qh] + 8.0f)) {  // defer-max (T13)
                float nm = fmaxf(mrow[qh], mx);
                float f = exp2b(mrow[qh] - nm);
                mrow[qh] = nm;
                lsum[qh] *= f;
#pragma unroll
                for (int mt = 0; mt < 4; ++mt)
#pragma unroll
                    for (int i = 0; i < 4; ++i) o[qh][mt][i] *= f;
            }
            float p[4][4];
            float ls = 0.f;
#pragma unroll
            for (int mt = 0; mt < 4; ++mt)
#pragma unroll
                for (int i = 0; i < 4; ++i) {
                    p[mt][i] = exp2b(s[qh][mt][i] - mrow[qh]);
                    ls += p[mt][i];
                }
            ls += __shfl_xor(ls, 16);
            ls += __shfl_xor(ls, 32);
            lsum[qh] += ls;

#pragma unroll
            for (int mt = 0; mt < 4; ++mt) {
                uint2 pr;
                pr.x = cvt_pk_bf16(p[mt][0], p[mt][1]);
                pr.y = cvt_pk_bf16(p[mt][2], p[mt][3]);
                *(uint2*)(&pw[(qh * 16 + lr) * PLDT + mt * 16 + lg * 4]) = pr;
            }
        }

        // O^T += V^T . P^T  (V fragments from LDS)
        bf16x8 vf[2][4];
#pragma unroll
        for (int ks = 0; ks < 2; ++ks)
#pragma unroll
            for (int mt = 0; mt < 4; ++mt)
                vf[ks][mt] = *(const bf16x8*)(v_lds + (mt * 16 + lr) * LDT + ks * 32 + lg * 8);

        __builtin_amdgcn_s_setprio(1);
#pragma unroll
        for (int qh = 0; qh < 2; ++qh)
#pragma unroll
            for (int ks = 0; ks < 2; ++ks) {
                bf16x8 pfr = *(const bf16x8*)(&pw[(qh * 16 + lr) * PLDT + ks * 32 + lg * 8]);
#pragma unroll
                for (int mt = 0; mt < 4; ++mt)
                    o[qh][mt] = __builtin_amdgcn_mfma_f32_16x16x32_bf16(vf[ks][mt], pfr, o[qh][mt], 0, 0, 0);
            }
        __builtin_amdgcn_s_setprio(0);
    }

    // epilogue (wave-private): transpose O^T -> [q][d] then coalesced stores
    float* ep = (float*)pw;
#pragma unroll
    for (int qh = 0; qh < 2; ++qh) {
        float rinv = 1.0f / lsum[qh];
#pragma unroll
        for (int mt = 0; mt < 4; ++mt)
#pragma unroll
            for (int i = 0; i < 4; ++i)
                ep[lr * 68 + mt * 16 + lg * 4 + i] = o[qh][mt][i] * rinv;
#pragma unroll
        for (int j = 0; j < 4; ++j) {
            int id = lane + 64 * j;
            int row = id >> 4;
            int c4 = (id & 15) << 2;
            float4 val = *(const float4*)(&ep[row * 68 + c4]);
            *(float4*)(&Out[((size_t)b * 2048 + q0 + w * 32 + qh * 16 + row) * 1024 + h * 64 + c4]) = val;
        }
    }
}

extern "C" void kernel_launch(void* const* d_in, const int* in_sizes, int n_in,
                              void* d_out, int out_size, void* d_ws, size_t ws_size,
                              hipStream_t stream) {
    const float* v = (const float*)d_in[0];
    const float* k = (const float*)d_in[1];
    const float* q = (const float*)d_in[2];
    const unsigned char* mask = (const unsigned char*)d_in[3];
    const float* Wq = (const float*)d_in[4];
    const float* bq = (const float*)d_in[5];
    const float* Wk = (const float*)d_in[6];
    const float* bk = (const float*)d_in[7];
    const float* Wv = (const float*)d_in[8];
    const float* bv = (const float*)d_in[9];
    float* out = (float*)d_out;

    unsigned short* qws = (unsigned short*)d_ws;
    unsigned short* kws = qws + 4194304;
    unsigned short* vws = kws + 4194304;

    dim3 pgrid(32, 8, 3);
    proj_gemm_all<<<pgrid, 256, 0, stream>>>(q, k, v, Wq, Wk, Wv, bq, bk, bv,
                                             qws, kws, vws);

    attn_kernel<<<dim3(512), 256, 0, stream>>>(qws, kws, vws, mask, out);
}